// Round 1
// baseline (548.993 us; speedup 1.0000x reference)
//
#include <hip/hip_runtime.h>

#define EDGE_K 32

__global__ __launch_bounds__(64) void spatial_edge_kernel(
    const float* __restrict__ pos,
    const int* __restrict__ n2g,
    const int* __restrict__ a2r,
    int* __restrict__ out,
    int n)
{
    int i = blockIdx.x * blockDim.x + threadIdx.x;
    if (i >= n) return;

    const float xi = pos[3*i+0];
    const float yi = pos[3*i+1];
    const float zi = pos[3*i+2];
    const float si = xi*xi + yi*yi + zi*zi;
    const int g  = n2g[i];
    const int ri = a2r[i];

    // node2graph is sorted -> same-graph nodes are a contiguous range.
    int lo = 0, hi = n;
    while (lo < hi) { int m = (lo + hi) >> 1; if (n2g[m] < g) lo = m + 1; else hi = m; }
    const int jstart = lo;
    hi = n;
    while (lo < hi) { int m = (lo + hi) >> 1; if (n2g[m] <= g) lo = m + 1; else hi = m; }
    const int jend = lo;

    // Insertion-sorted top-K by (d2 asc, j asc) — matches jax.lax.top_k
    // stability (ties -> lower index first) because we scan j ascending and
    // use strict compares.
    float bd[EDGE_K];
    int   bj[EDGE_K];
    int cnt = 0;

    for (int j = jstart; j < jend; ++j) {
        if (j == i) continue;
        const float xj = pos[3*j+0];
        const float yj = pos[3*j+1];
        const float zj = pos[3*j+2];
        const float sj  = xj*xj + yj*yj + zj*zj;
        const float dt  = xi*xj + yi*yj + zi*zj;
        float d2 = si + sj - 2.0f*dt;          // exact reference formula
        d2 = fmaxf(d2, 0.0f);
        if (d2 > 25.0f) continue;              // RADIUS^2
        if (cnt == EDGE_K && d2 >= bd[EDGE_K-1]) continue;
        int p = (cnt < EDGE_K) ? cnt : (EDGE_K - 1);
        while (p > 0 && bd[p-1] > d2) {
            bd[p] = bd[p-1];
            bj[p] = bj[p-1];
            --p;
        }
        bd[p] = d2;
        bj[p] = j;
        if (cnt < EDGE_K) ++cnt;
    }

    const int NK = n * EDGE_K;
    int* valid_out = out + 3 * NK;
    for (int k = 0; k < EDGE_K; ++k) {
        int a = -1, b = -1, c = -1, v = 0;
        if (k < cnt) {
            const int j  = bj[k];
            const int rj = a2r[j];
            const int rd = (rj > ri) ? (rj - ri) : (ri - rj);
            const float dx = pos[3*j+0] - xi;
            const float dy = pos[3*j+1] - yi;
            const float dz = pos[3*j+2] - zi;
            const float d2s = dx*dx + dy*dy + dz*dz;   // direct-diff filter
            if (rd >= 5 && d2s >= 1e-20f) { a = j; b = i; c = 0; v = 1; }
        }
        const int e = i * EDGE_K + k;
        out[3*e+0] = a;
        out[3*e+1] = b;
        out[3*e+2] = c;
        valid_out[e] = v;
    }
    if (i == 0) out[4*NK] = 1;   // the jnp.int32(1) scalar output
}

extern "C" void kernel_launch(void* const* d_in, const int* in_sizes, int n_in,
                              void* d_out, int out_size, void* d_ws, size_t ws_size,
                              hipStream_t stream) {
    const float* pos = (const float*)d_in[0];
    const int*   n2g = (const int*)d_in[1];
    const int*   a2r = (const int*)d_in[2];
    int* out = (int*)d_out;
    const int n = in_sizes[0] / 3;
    const int block = 64;
    const int grid = (n + block - 1) / block;
    hipLaunchKernelGGL(spatial_edge_kernel, dim3(grid), dim3(block), 0, stream,
                       pos, n2g, a2r, out, n);
}

// Round 2
// 33.862 us; speedup vs baseline: 16.2127x; 16.2127x over previous
//
#include <hip/hip_runtime.h>

#define EDGE_K 32
#define CAP    256   // per-node candidate cap before serial fallback

__global__ __launch_bounds__(64) void spatial_edge_kernel(
    const float* __restrict__ pos,
    const int* __restrict__ n2g,
    const int* __restrict__ a2r,
    int* __restrict__ out,
    int n)
{
    const int i    = blockIdx.x;      // one wave per node
    const int lane = threadIdx.x;

    __shared__ float sd2[CAP];
    __shared__ int   sj[CAP];
    __shared__ float rd2[EDGE_K];
    __shared__ int   rj[EDGE_K];

    const float xi = pos[3*i+0];
    const float yi = pos[3*i+1];
    const float zi = pos[3*i+2];
    const float si = xi*xi + yi*yi + zi*zi;
    const int g  = n2g[i];
    const int ri = a2r[i];

    // node2graph is sorted -> same-graph nodes are a contiguous range.
    // (redundant uniform binary search on all lanes; broadcast loads)
    int lo = 0, hi = n;
    while (lo < hi) { int m = (lo + hi) >> 1; if (n2g[m] < g) lo = m + 1; else hi = m; }
    const int jstart = lo;
    hi = n;
    while (lo < hi) { int m = (lo + hi) >> 1; if (n2g[m] <= g) lo = m + 1; else hi = m; }
    const int jend = lo;

    // --- parallel scan: lanes stride the candidate range, ballot-compact to LDS
    int count = 0;
    for (int j0 = jstart; j0 < jend; j0 += 64) {
        const int j = j0 + lane;
        bool pass = false;
        float d2 = 0.0f;
        if (j < jend && j != i) {
            const float xj = pos[3*j+0];
            const float yj = pos[3*j+1];
            const float zj = pos[3*j+2];
            const float sj2 = xj*xj + yj*yj + zj*zj;
            const float dt  = xi*xj + yi*yj + zi*zj;
            d2 = si + sj2 - 2.0f*dt;           // exact reference formula
            d2 = fmaxf(d2, 0.0f);
            pass = (d2 <= 25.0f);
        }
        const unsigned long long mask = __ballot(pass);
        if (pass) {
            const int idx = count + __popcll(mask & ((1ull << lane) - 1ull));
            if (idx < CAP) { sd2[idx] = d2; sj[idx] = j; }
        }
        count += __popcll(mask);
    }
    __syncthreads();

    int cnt;  // number of valid output slots
    if (count <= CAP) {
        // --- rank-based stable sort: rank = #{(d2',j') < (d2,j)} lexicographic
        const int m = count;
        for (int c = lane; c < m; c += 64) {
            const float dc = sd2[c];
            const int   jc = sj[c];
            int rank = 0;
            for (int t = 0; t < m; ++t) {
                const float dt_ = sd2[t];
                const int   jt  = sj[t];
                rank += (dt_ < dc) || (dt_ == dc && jt < jc);
            }
            if (rank < EDGE_K) { rd2[rank] = dc; rj[rank] = jc; }
        }
        cnt = (m < EDGE_K) ? m : EDGE_K;
    } else {
        // --- serial fallback (astronomically rare): lane 0 redoes insertion top-K
        if (lane == 0) {
            float bd[EDGE_K];
            int   bj[EDGE_K];
            int c2 = 0;
            for (int j = jstart; j < jend; ++j) {
                if (j == i) continue;
                const float xj = pos[3*j+0];
                const float yj = pos[3*j+1];
                const float zj = pos[3*j+2];
                const float sj2 = xj*xj + yj*yj + zj*zj;
                const float dt  = xi*xj + yi*yj + zi*zj;
                float d2 = si + sj2 - 2.0f*dt;
                d2 = fmaxf(d2, 0.0f);
                if (d2 > 25.0f) continue;
                if (c2 == EDGE_K && d2 >= bd[EDGE_K-1]) continue;
                int p = (c2 < EDGE_K) ? c2 : (EDGE_K - 1);
                while (p > 0 && bd[p-1] > d2) {
                    bd[p] = bd[p-1]; bj[p] = bj[p-1]; --p;
                }
                bd[p] = d2; bj[p] = j;
                if (c2 < EDGE_K) ++c2;
            }
            for (int k = 0; k < c2; ++k) { rd2[k] = bd[k]; rj[k] = bj[k]; }
        }
        cnt = (count < EDGE_K) ? count : EDGE_K;
    }
    __syncthreads();

    // --- epilogue: lanes 0..31 write one output row each
    const int NK = n * EDGE_K;
    int* valid_out = out + 3 * NK;
    if (lane < EDGE_K) {
        const int k = lane;
        int a = -1, b = -1, c = -1, v = 0;
        if (k < cnt) {
            const int j  = rj[k];
            const int rjres = a2r[j];
            const int rd = (rjres > ri) ? (rjres - ri) : (ri - rjres);
            const float dx = pos[3*j+0] - xi;
            const float dy = pos[3*j+1] - yi;
            const float dz = pos[3*j+2] - zi;
            const float d2s = dx*dx + dy*dy + dz*dz;
            if (rd >= 5 && d2s >= 1e-20f) { a = j; b = i; c = 0; v = 1; }
        }
        const int e = i * EDGE_K + k;
        out[3*e+0] = a;
        out[3*e+1] = b;
        out[3*e+2] = c;
        valid_out[e] = v;
    }
    if (i == 0 && lane == 0) out[4*NK] = 1;   // the jnp.int32(1) scalar output
}

extern "C" void kernel_launch(void* const* d_in, const int* in_sizes, int n_in,
                              void* d_out, int out_size, void* d_ws, size_t ws_size,
                              hipStream_t stream) {
    const float* pos = (const float*)d_in[0];
    const int*   n2g = (const int*)d_in[1];
    const int*   a2r = (const int*)d_in[2];
    int* out = (int*)d_out;
    const int n = in_sizes[0] / 3;
    hipLaunchKernelGGL(spatial_edge_kernel, dim3(n), dim3(64), 0, stream,
                       pos, n2g, a2r, out, n);
}